// Round 10
// baseline (105.862 us; speedup 1.0000x reference)
//
#include <hip/hip_runtime.h>

// MechanicsPINN: residual = EI*biharm(f) + GC*lap(f) + KC*f - P,
// f = MLP(x) 2->256->512->1024->65536, B=64, grid 256x256. All inputs fp32.
// Round 10: R8/R9 zero-barrier reg-staged bf16 MFMA GEMM, but block = 32
// n-cols (grid 2048 -> 8 blocks/CU -> 2 waves/SIMD TLP; R9 had 1 wave/SIMD,
// fully exposing the per-step serial chain). Per-step work halved; LDS write
// swizzle (colgrp ^ k&7) -> conflict-free b128 writes; ~110 VGPR.

#define BATCH 64
#define NPIX 65536

typedef __attribute__((ext_vector_type(8))) short short8_t;  // bf16 x8 (4 VGPR)
typedef __attribute__((ext_vector_type(4))) float f32x4;

#define LDS_FENCE()   asm volatile("s_waitcnt lgkmcnt(0)" ::: "memory")
#define MEM_ORDER()   asm volatile("" ::: "memory")

__device__ __forceinline__ short f2bf(float x) {  // fp32 -> bf16 RNE
    unsigned u = __float_as_uint(x);
    unsigned r = (u + 0x7fffu + ((u >> 16) & 1u)) >> 16;
    return (short)r;
}

// -------- Fused layers 1+2: h2 = relu(relu(x@W1+b1) @ W2 + b2) --------
__global__ void k_layer12(const float* __restrict__ x, const float* __restrict__ W1,
                          const float* __restrict__ b1, const float* __restrict__ W2,
                          const float* __restrict__ b2, float* __restrict__ h2) {
    __shared__ float As[16][64];
    __shared__ float Ws[64][16];
    int tid = threadIdx.x;
    int tn = tid & 15, tm = tid >> 4;
    int n0 = blockIdx.x * 16, m0 = blockIdx.y * 16;
    float acc = 0.f;
    for (int k0 = 0; k0 < 256; k0 += 64) {
#pragma unroll
        for (int j = 0; j < 4; ++j) {          // build h1 16x64 tile on the fly
            int e = j * 256 + tid;
            int m = m0 + (e >> 6), kk = k0 + (e & 63);
            float v = x[m * 2 + 0] * W1[kk] + x[m * 2 + 1] * W1[256 + kk] + b1[kk];
            As[e >> 6][e & 63] = v > 0.f ? v : 0.f;
        }
#pragma unroll
        for (int j = 0; j < 4; ++j) {          // stage W2 64x16
            int e = j * 256 + tid;
            Ws[e >> 4][e & 15] = W2[(k0 + (e >> 4)) * 512 + n0 + (e & 15)];
        }
        __syncthreads();
#pragma unroll
        for (int k = 0; k < 64; ++k)
            acc += As[tm][k] * Ws[k][tn];
        __syncthreads();
    }
    acc += b2[n0 + tn];
    acc = acc > 0.f ? acc : 0.f;
    h2[(m0 + tm) * 512 + n0 + tn] = acc;
}

// -------- Layer 3: h3b(bf16) = relu(h2 @ W3 + b3), K=512, N=1024 --------
__global__ void k_layer3(const float* __restrict__ A, const float* __restrict__ Wt,
                         const float* __restrict__ bias, short* __restrict__ out_bf) {
    __shared__ float As[16][64];
    __shared__ float Ws[64][16];
    int tid = threadIdx.x;
    int tn = tid & 15, tm = tid >> 4;
    int n0 = blockIdx.x * 16, m0 = blockIdx.y * 16;
    float acc = 0.f;
    for (int k0 = 0; k0 < 512; k0 += 64) {
#pragma unroll
        for (int j = 0; j < 4; ++j) {
            int e = j * 256 + tid;
            As[e >> 6][e & 63] = A[(m0 + (e >> 6)) * 512 + k0 + (e & 63)];
        }
#pragma unroll
        for (int j = 0; j < 4; ++j) {
            int e = j * 256 + tid;
            Ws[e >> 4][e & 15] = Wt[(k0 + (e >> 4)) * 1024 + n0 + (e & 15)];
        }
        __syncthreads();
#pragma unroll
        for (int k = 0; k < 64; ++k)
            acc += As[tm][k] * Ws[k][tn];
        __syncthreads();
    }
    acc += bias[n0 + tn];
    acc = acc > 0.f ? acc : 0.f;
    out_bf[(m0 + tm) * 1024 + n0 + tn] = f2bf(acc);
}

// ---------- Main GEMM: f = h3b @ W4 + b4 (bf16 MFMA, M=64,N=65536,K=1024) ----
// One wave per block; wave owns 32 cols x all 64 m = 8 MFMA per 32-k step.
// Grid 2048 -> 8 blocks/CU -> 2 waves/SIMD.
__global__ __launch_bounds__(64) void k_gemm_mfma(
        const short* __restrict__ A,     // h3 bf16 [64][1024]
        const float* __restrict__ W,     // W4 fp32 [1024][65536]
        const float* __restrict__ bias,  // [65536]
        float* __restrict__ f) {         // [64][65536]
    __shared__ float Bl[32 * 32];        // 4KB wave-private [k][colgrp swz]
    const int lane = threadIdx.x;
    const int lr = lane & 15;
    const int g = lane >> 4;             // k-group 0..3
    const int n0w = blockIdx.x * 32;
    const int kl = ((lane >> 4) << 1) | ((lane >> 3) & 1);  // k sub-row 0..7
    const int cg = lane & 7;             // col-group 0..7 (4 cols each)

    f32x4 acc[4][2];                     // [m-tile][n-tile]
#pragma unroll
    for (int a = 0; a < 4; ++a)
#pragma unroll
        for (int b = 0; b < 2; ++b)
            acc[a][b] = {0.f, 0.f, 0.f, 0.f};

    const short* ap = A + lr * 1024 + g * 8;

    f32x4 RA[4], RB[4];                  // 2 staging sets, 16 VGPR each
    // gload: instr i covers k-rows {i*8 + kl}, 128B contiguous per row
    auto gloadA = [&](int k0) {
#pragma unroll
        for (int i = 0; i < 4; ++i)
            RA[i] = *(const f32x4*)(W + (size_t)(k0 + i * 8 + kl) * NPIX + n0w + cg * 4);
    };
    auto gloadB = [&](int k0) {
#pragma unroll
        for (int i = 0; i < 4; ++i)
            RB[i] = *(const f32x4*)(W + (size_t)(k0 + i * 8 + kl) * NPIX + n0w + cg * 4);
    };
    // LDS (k, colgrp q): float idx k*32 + (q ^ (k&7))*4 ; writes conflict-free
    auto lwriteA = [&]() {
#pragma unroll
        for (int i = 0; i < 4; ++i)
            *(f32x4*)&Bl[(i * 8 + kl) * 32 + ((cg ^ kl) << 2)] = RA[i];
    };
    auto lwriteB = [&]() {
#pragma unroll
        for (int i = 0; i < 4; ++i)
            *(f32x4*)&Bl[(i * 8 + kl) * 32 + ((cg ^ kl) << 2)] = RB[i];
    };

    short8_t aC[4], aN[4];

    auto compute = [&]() {
#pragma unroll
        for (int t = 0; t < 2; ++t) {
            short8_t bf;
#pragma unroll
            for (int j = 0; j < 8; ++j)   // col=t*16+lr, k=g*8+j
                bf[j] = f2bf(Bl[(g * 8 + j) * 32 +
                                (((((t << 2) + (lr >> 2)) ^ j) & 7) << 2) + (lr & 3)]);
#pragma unroll
            for (int mt = 0; mt < 4; ++mt)
                acc[mt][t] = __builtin_amdgcn_mfma_f32_16x16x32_bf16(aC[mt], bf, acc[mt][t], 0, 0, 0);
        }
    };
    auto advanceA = [&](int s) {         // aC <- A(s+1), prefetch A(s+2)
#pragma unroll
        for (int mt = 0; mt < 4; ++mt) aC[mt] = aN[mt];
        if (s + 2 < 32) {
#pragma unroll
            for (int mt = 0; mt < 4; ++mt)
                aN[mt] = *(const short8_t*)(ap + mt * 16384 + (s + 2) * 32);
        }
    };

    // prologue: tile0 -> RA -> LDS; tile1 -> RB; tile2 -> RA; A(0),A(1)
    gloadA(0);
    gloadB(32);
#pragma unroll
    for (int mt = 0; mt < 4; ++mt)
        aC[mt] = *(const short8_t*)(ap + mt * 16384);
#pragma unroll
    for (int mt = 0; mt < 4; ++mt)
        aN[mt] = *(const short8_t*)(ap + mt * 16384 + 32);
    lwriteA();                           // waits tile0 only (counted vmcnt)
    gloadA(64);                          // tile2 back in flight
    LDS_FENCE();                         // tile0 visible to all lanes

    // steady loop: even step stages from RB, odd from RA; 2-step issue slack
    for (int t2 = 0; t2 < 16; ++t2) {
        const int s0 = 2 * t2;
        compute();
        MEM_ORDER();                     // reads before the overwrite below
        if (s0 < 31) {
            lwriteB();                   // waits tile s0+1 (issued 2 steps ago)
            LDS_FENCE();
            if (s0 < 29) gloadB((s0 + 3) * 32);
        }
        advanceA(s0);
        const int s1 = s0 + 1;
        compute();
        MEM_ORDER();
        if (s1 < 31) {
            lwriteA();
            LDS_FENCE();
            if (s1 < 29) gloadA((s1 + 3) * 32);
        }
        advanceA(s1);
    }

    // epilogue: coalesce C through LDS, 32 rows at a time (Bl = 32x32 f32)
#pragma unroll
    for (int h = 0; h < 2; ++h) {
        MEM_ORDER();                     // WAR: prior reads before overwrite
#pragma unroll
        for (int mtl = 0; mtl < 2; ++mtl) {
            int mt = h * 2 + mtl;
#pragma unroll
            for (int t = 0; t < 2; ++t) {
                float bb = bias[n0w + t * 16 + lr];
#pragma unroll
                for (int r = 0; r < 4; ++r)
                    Bl[(mtl * 16 + g * 4 + r) * 32 + t * 16 + lr] = acc[mt][t][r] + bb;
            }
        }
        LDS_FENCE();                     // cross-lane visibility for the reads
#pragma unroll
        for (int jj = 0; jj < 4; ++jj) {
            int rl = jj * 8 + (lane >> 3);       // local row 0..31
            f32x4 v = *(const f32x4*)&Bl[rl * 32 + (lane & 7) * 4];
            *(f32x4*)(f + (size_t)(h * 32 + rl) * NPIX + n0w + (lane & 7) * 4) = v;
        }
        MEM_ORDER();
    }
}

// --------------------------- Stencil ---------------------------
// residual = biharm + lap + f - P; reflect-1 index reflection.
#define ROWS 16
__device__ __forceinline__ int rfl(int i) {
    return i < 0 ? -i : (i > 255 ? 510 - i : i);
}
__global__ void k_stencil(const float* __restrict__ f, const float* __restrict__ P,
                          float* __restrict__ out) {
    __shared__ float fs[ROWS + 4][256];
    int x = threadIdx.x;
    int y0 = blockIdx.x * ROWS;
    int b = blockIdx.y;
    const float* fb = f + (size_t)b * NPIX;
    for (int t = 0; t < ROWS + 4; ++t) {
        int gy = rfl(y0 - 2 + t);
        fs[t][x] = fb[gy * 256 + x];
    }
    __syncthreads();

    int xm = x == 0 ? 1 : x - 1;
    int xp = x == 255 ? 254 : x + 1;

    auto lapAt = [&](int j, int i) {
        int s = j - y0 + 2;
        int sm = rfl(j - 1) - y0 + 2;
        int sp = rfl(j + 1) - y0 + 2;
        int im = i == 0 ? 1 : i - 1;
        int ip = i == 255 ? 254 : i + 1;
        float c = fs[s][i];
        return (fs[sm][i] - 2.f * c + fs[sp][i]) + (fs[s][im] - 2.f * c + fs[s][ip]);
    };

    for (int r = 0; r < ROWS; ++r) {
        int y = y0 + r;
        float lc = lapAt(y, x);
        float lym = lapAt(rfl(y - 1), x);
        float lyp = lapAt(rfl(y + 1), x);
        float lxm = lapAt(y, xm);
        float lxp = lapAt(y, xp);
        float bih = (lym - 2.f * lc + lyp) + (lxm - 2.f * lc + lxp);
        float fc = fs[r + 2][x];
        size_t idx = (size_t)b * NPIX + y * 256 + x;
        out[idx] = bih + lc + fc - P[idx];
    }
}

extern "C" void kernel_launch(void* const* d_in, const int* in_sizes, int n_in,
                              void* d_out, int out_size, void* d_ws, size_t ws_size,
                              hipStream_t stream) {
    const float* x  = (const float*)d_in[0];
    const float* P  = (const float*)d_in[1];
    const float* W1 = (const float*)d_in[2];
    const float* b1 = (const float*)d_in[3];
    const float* W2 = (const float*)d_in[4];
    const float* b2 = (const float*)d_in[5];
    const float* W3 = (const float*)d_in[6];
    const float* b3 = (const float*)d_in[7];
    const float* W4 = (const float*)d_in[8];
    const float* b4 = (const float*)d_in[9];
    float* out = (float*)d_out;

    char* ws = (char*)d_ws;
    float* h2  = (float*)(ws);                      // 64*512*4  = 128 KB
    short* h3b = (short*)(ws + (128 << 10));        // 64*1024*2 = 128 KB (bf16)
    float* f   = (float*)(ws + (256 << 10));        // 64*65536*4 = 16 MB

    k_layer12<<<dim3(512 / 16, 4), 256, 0, stream>>>(x, W1, b1, W2, b2, h2);
    k_layer3<<<dim3(1024 / 16, 4), 256, 0, stream>>>(h2, W3, b3, h3b);
    k_gemm_mfma<<<NPIX / 32, 64, 0, stream>>>(h3b, W4, b4, f);
    k_stencil<<<dim3(256 / ROWS, BATCH), 256, 0, stream>>>(f, P, out);
}

// Round 11
// 94.020 us; speedup vs baseline: 1.1259x; 1.1259x over previous
//
#include <hip/hip_runtime.h>

// MechanicsPINN: residual = EI*biharm(f) + GC*lap(f) + KC*f - P,
// f = MLP(x) 2->256->512->1024->65536, B=64, grid 256x256. All inputs fp32.
// Round 11: R9 pipeline, split-K across 2 waves per block (128 thr).
// Wave w does K-steps s=2i+w with the identical zero-barrier reg-staged
// pipeline (64-col tiles, 256B segments, RA/RB 2-deep, lgkm-only fences,
// private 8KB LDS half). Grid 1024 -> 8 waves/CU = 2 waves/SIMD (R9 had 1).
// One-time split-K reduction at the end (2 syncthreads).

#define BATCH 64
#define NPIX 65536

typedef __attribute__((ext_vector_type(8))) short short8_t;  // bf16 x8 (4 VGPR)
typedef __attribute__((ext_vector_type(4))) float f32x4;

#define LDS_FENCE()   asm volatile("s_waitcnt lgkmcnt(0)" ::: "memory")
#define MEM_ORDER()   asm volatile("" ::: "memory")

__device__ __forceinline__ short f2bf(float x) {  // fp32 -> bf16 RNE
    unsigned u = __float_as_uint(x);
    unsigned r = (u + 0x7fffu + ((u >> 16) & 1u)) >> 16;
    return (short)r;
}

// -------- Fused layers 1+2: h2 = relu(relu(x@W1+b1) @ W2 + b2) --------
__global__ void k_layer12(const float* __restrict__ x, const float* __restrict__ W1,
                          const float* __restrict__ b1, const float* __restrict__ W2,
                          const float* __restrict__ b2, float* __restrict__ h2) {
    __shared__ float As[16][64];
    __shared__ float Ws[64][16];
    int tid = threadIdx.x;
    int tn = tid & 15, tm = tid >> 4;
    int n0 = blockIdx.x * 16, m0 = blockIdx.y * 16;
    float acc = 0.f;
    for (int k0 = 0; k0 < 256; k0 += 64) {
#pragma unroll
        for (int j = 0; j < 4; ++j) {          // build h1 16x64 tile on the fly
            int e = j * 256 + tid;
            int m = m0 + (e >> 6), kk = k0 + (e & 63);
            float v = x[m * 2 + 0] * W1[kk] + x[m * 2 + 1] * W1[256 + kk] + b1[kk];
            As[e >> 6][e & 63] = v > 0.f ? v : 0.f;
        }
#pragma unroll
        for (int j = 0; j < 4; ++j) {          // stage W2 64x16
            int e = j * 256 + tid;
            Ws[e >> 4][e & 15] = W2[(k0 + (e >> 4)) * 512 + n0 + (e & 15)];
        }
        __syncthreads();
#pragma unroll
        for (int k = 0; k < 64; ++k)
            acc += As[tm][k] * Ws[k][tn];
        __syncthreads();
    }
    acc += b2[n0 + tn];
    acc = acc > 0.f ? acc : 0.f;
    h2[(m0 + tm) * 512 + n0 + tn] = acc;
}

// -------- Layer 3: h3b(bf16) = relu(h2 @ W3 + b3), K=512, N=1024 --------
__global__ void k_layer3(const float* __restrict__ A, const float* __restrict__ Wt,
                         const float* __restrict__ bias, short* __restrict__ out_bf) {
    __shared__ float As[16][64];
    __shared__ float Ws[64][16];
    int tid = threadIdx.x;
    int tn = tid & 15, tm = tid >> 4;
    int n0 = blockIdx.x * 16, m0 = blockIdx.y * 16;
    float acc = 0.f;
    for (int k0 = 0; k0 < 512; k0 += 64) {
#pragma unroll
        for (int j = 0; j < 4; ++j) {
            int e = j * 256 + tid;
            As[e >> 6][e & 63] = A[(m0 + (e >> 6)) * 512 + k0 + (e & 63)];
        }
#pragma unroll
        for (int j = 0; j < 4; ++j) {
            int e = j * 256 + tid;
            Ws[e >> 4][e & 15] = Wt[(k0 + (e >> 4)) * 1024 + n0 + (e & 15)];
        }
        __syncthreads();
#pragma unroll
        for (int k = 0; k < 64; ++k)
            acc += As[tm][k] * Ws[k][tn];
        __syncthreads();
    }
    acc += bias[n0 + tn];
    acc = acc > 0.f ? acc : 0.f;
    out_bf[(m0 + tm) * 1024 + n0 + tn] = f2bf(acc);
}

// ---------- Main GEMM: f = h3b @ W4 + b4 (bf16 MFMA, M=64,N=65536,K=1024) ----
// 128 threads = 2 waves. Wave w: K-steps s=2i+w (i=0..15), 64 cols x 64 m,
// private LDS half, R9 pipeline verbatim. Split-K reduce at end.
__global__ __launch_bounds__(128) void k_gemm_mfma(
        const short* __restrict__ A,     // h3 bf16 [64][1024]
        const float* __restrict__ W,     // W4 fp32 [1024][65536]
        const float* __restrict__ bias,  // [65536]
        float* __restrict__ f) {         // [64][65536]
    __shared__ float Bl[2][32 * 64];     // per-wave 8KB staging; reused as 16KB AccBuf
    const int tid = threadIdx.x;
    const int wv = tid >> 6;
    const int lane = tid & 63;
    const int lr = lane & 15;
    const int g = lane >> 4;             // k-group 0..3
    const int n0w = blockIdx.x * 64;
    const int kof = lane >> 4;           // k sub-row 0..3
    const int cof = (lane & 15) * 4;     // col offset
    float* Blw = &Bl[wv][0];

    f32x4 acc[4][4];                     // [m-tile][n-tile]
#pragma unroll
    for (int a = 0; a < 4; ++a)
#pragma unroll
        for (int b = 0; b < 4; ++b)
            acc[a][b] = {0.f, 0.f, 0.f, 0.f};

    const short* ap = A + lr * 1024 + g * 8;

    f32x4 RA[8], RB[8];                  // 2 staging sets, 32 VGPR each
    // tile index i -> global k-step s = 2i+wv, k0 = s*32
    auto gloadA = [&](int i) {
        const float* wp = W + (size_t)((2 * i + wv) * 32) * NPIX + n0w + cof;
#pragma unroll
        for (int q = 0; q < 8; ++q)
            RA[q] = *(const f32x4*)(wp + (size_t)(q * 4 + kof) * NPIX);
    };
    auto gloadB = [&](int i) {
        const float* wp = W + (size_t)((2 * i + wv) * 32) * NPIX + n0w + cof;
#pragma unroll
        for (int q = 0; q < 8; ++q)
            RB[q] = *(const f32x4*)(wp + (size_t)(q * 4 + kof) * NPIX);
    };
    // LDS element (k,col) at float idx k*64 + (col ^ ((k>>3)<<4))
    auto lwriteA = [&]() {
#pragma unroll
        for (int q = 0; q < 8; ++q) {
            int k = q * 4 + kof;
            int cc = cof ^ (((q >> 1) & 3) << 4);
            *(f32x4*)&Blw[k * 64 + cc] = RA[q];
        }
    };
    auto lwriteB = [&]() {
#pragma unroll
        for (int q = 0; q < 8; ++q) {
            int k = q * 4 + kof;
            int cc = cof ^ (((q >> 1) & 3) << 4);
            *(f32x4*)&Blw[k * 64 + cc] = RB[q];
        }
    };

    short8_t aC[4], aN[4];

    auto compute = [&]() {
#pragma unroll
        for (int t = 0; t < 4; ++t) {
            const int csw = (t * 16 + lr) ^ (g << 4);
            short8_t bf;
#pragma unroll
            for (int j = 0; j < 8; ++j)
                bf[j] = f2bf(Blw[(g * 8 + j) * 64 + csw]);
#pragma unroll
            for (int mt = 0; mt < 4; ++mt)
                acc[mt][t] = __builtin_amdgcn_mfma_f32_16x16x32_bf16(aC[mt], bf, acc[mt][t], 0, 0, 0);
        }
    };
    auto advanceA = [&](int i) {         // aC <- A-frag(i+1), prefetch A-frag(i+2)
        if (i + 1 < 16) {
#pragma unroll
            for (int mt = 0; mt < 4; ++mt) aC[mt] = aN[mt];
        }
        if (i + 2 < 16) {
#pragma unroll
            for (int mt = 0; mt < 4; ++mt)
                aN[mt] = *(const short8_t*)(ap + mt * 16384 + (2 * (i + 2) + wv) * 32);
        }
    };

    // prologue: tile0 -> RA -> LDS; tile1 -> RB; tile2 -> RA; A(0),A(1)
    gloadA(0);
    gloadB(1);
#pragma unroll
    for (int mt = 0; mt < 4; ++mt)
        aC[mt] = *(const short8_t*)(ap + mt * 16384 + wv * 32);
#pragma unroll
    for (int mt = 0; mt < 4; ++mt)
        aN[mt] = *(const short8_t*)(ap + mt * 16384 + (2 + wv) * 32);
    lwriteA();                           // waits tile0 only (counted vmcnt)
    gloadA(2);                           // tile2 back in flight
    LDS_FENCE();                         // tile0 visible to all lanes of wave

    // steady loop: even tile from RA->LDS done, stage RB next; 2-tile slack
    for (int t2 = 0; t2 < 8; ++t2) {
        const int i0 = 2 * t2;
        compute();                       // tile i0
        MEM_ORDER();
        if (i0 < 15) {
            lwriteB();                   // tile i0+1 (issued 2 steps ago)
            LDS_FENCE();
            if (i0 < 13) gloadB(i0 + 3);
        }
        advanceA(i0);
        const int i1 = i0 + 1;
        compute();                       // tile i1
        MEM_ORDER();
        if (i1 < 15) {
            lwriteA();
            LDS_FENCE();
            if (i1 < 13) gloadA(i1 + 3);
        }
        advanceA(i1);
    }

    // ---- split-K reduction: wave1 dumps, wave0 adds + writes C ----
    __syncthreads();                     // all compute reads done
    if (wv == 1) {
        float* AccBuf = &Bl[0][0];       // 4096 floats = 16KB
#pragma unroll
        for (int mt = 0; mt < 4; ++mt)
#pragma unroll
            for (int t = 0; t < 4; ++t)
                *(f32x4*)&AccBuf[(mt * 4 + t) * 256 + lane * 4] = acc[mt][t];
    }
    __syncthreads();                     // dump visible
    if (wv == 1) return;

    {
        float* AccBuf = &Bl[0][0];
#pragma unroll
        for (int mt = 0; mt < 4; ++mt)
#pragma unroll
            for (int t = 0; t < 4; ++t) {
                f32x4 o = *(const f32x4*)&AccBuf[(mt * 4 + t) * 256 + lane * 4];
                acc[mt][t][0] += o[0]; acc[mt][t][1] += o[1];
                acc[mt][t][2] += o[2]; acc[mt][t][3] += o[3];
            }
    }
    MEM_ORDER();

    // epilogue (wave0 only): coalesce C through LDS, 32 rows at a time
    float* Ble = &Bl[0][0];
#pragma unroll
    for (int h = 0; h < 2; ++h) {
        MEM_ORDER();
#pragma unroll
        for (int mtl = 0; mtl < 2; ++mtl) {
            int mt = h * 2 + mtl;
#pragma unroll
            for (int t = 0; t < 4; ++t) {
                float bb = bias[n0w + t * 16 + lr];
#pragma unroll
                for (int r = 0; r < 4; ++r)
                    Ble[(mtl * 16 + g * 4 + r) * 64 + t * 16 + lr] = acc[mt][t][r] + bb;
            }
        }
        LDS_FENCE();                     // cross-lane visibility within wave0
#pragma unroll
        for (int jj = 0; jj < 8; ++jj) {
            int rl = jj * 4 + kof;       // local row 0..31
            f32x4 v = *(const f32x4*)&Ble[rl * 64 + cof];
            *(f32x4*)(f + (size_t)(h * 32 + rl) * NPIX + n0w + cof) = v;
        }
        MEM_ORDER();
    }
}

// --------------------------- Stencil ---------------------------
// residual = biharm + lap + f - P; reflect-1 index reflection.
#define ROWS 16
__device__ __forceinline__ int rfl(int i) {
    return i < 0 ? -i : (i > 255 ? 510 - i : i);
}
__global__ void k_stencil(const float* __restrict__ f, const float* __restrict__ P,
                          float* __restrict__ out) {
    __shared__ float fs[ROWS + 4][256];
    int x = threadIdx.x;
    int y0 = blockIdx.x * ROWS;
    int b = blockIdx.y;
    const float* fb = f + (size_t)b * NPIX;
    for (int t = 0; t < ROWS + 4; ++t) {
        int gy = rfl(y0 - 2 + t);
        fs[t][x] = fb[gy * 256 + x];
    }
    __syncthreads();

    int xm = x == 0 ? 1 : x - 1;
    int xp = x == 255 ? 254 : x + 1;

    auto lapAt = [&](int j, int i) {
        int s = j - y0 + 2;
        int sm = rfl(j - 1) - y0 + 2;
        int sp = rfl(j + 1) - y0 + 2;
        int im = i == 0 ? 1 : i - 1;
        int ip = i == 255 ? 254 : i + 1;
        float c = fs[s][i];
        return (fs[sm][i] - 2.f * c + fs[sp][i]) + (fs[s][im] - 2.f * c + fs[s][ip]);
    };

    for (int r = 0; r < ROWS; ++r) {
        int y = y0 + r;
        float lc = lapAt(y, x);
        float lym = lapAt(rfl(y - 1), x);
        float lyp = lapAt(rfl(y + 1), x);
        float lxm = lapAt(y, xm);
        float lxp = lapAt(y, xp);
        float bih = (lym - 2.f * lc + lyp) + (lxm - 2.f * lc + lxp);
        float fc = fs[r + 2][x];
        size_t idx = (size_t)b * NPIX + y * 256 + x;
        out[idx] = bih + lc + fc - P[idx];
    }
}

extern "C" void kernel_launch(void* const* d_in, const int* in_sizes, int n_in,
                              void* d_out, int out_size, void* d_ws, size_t ws_size,
                              hipStream_t stream) {
    const float* x  = (const float*)d_in[0];
    const float* P  = (const float*)d_in[1];
    const float* W1 = (const float*)d_in[2];
    const float* b1 = (const float*)d_in[3];
    const float* W2 = (const float*)d_in[4];
    const float* b2 = (const float*)d_in[5];
    const float* W3 = (const float*)d_in[6];
    const float* b3 = (const float*)d_in[7];
    const float* W4 = (const float*)d_in[8];
    const float* b4 = (const float*)d_in[9];
    float* out = (float*)d_out;

    char* ws = (char*)d_ws;
    float* h2  = (float*)(ws);                      // 64*512*4  = 128 KB
    short* h3b = (short*)(ws + (128 << 10));        // 64*1024*2 = 128 KB (bf16)
    float* f   = (float*)(ws + (256 << 10));        // 64*65536*4 = 16 MB

    k_layer12<<<dim3(512 / 16, 4), 256, 0, stream>>>(x, W1, b1, W2, b2, h2);
    k_layer3<<<dim3(1024 / 16, 4), 256, 0, stream>>>(h2, W3, b3, h3b);
    k_gemm_mfma<<<NPIX / 64, 128, 0, stream>>>(h3b, W4, b4, f);
    k_stencil<<<dim3(256 / ROWS, BATCH), 256, 0, stream>>>(f, P, out);
}

// Round 12
// 87.393 us; speedup vs baseline: 1.2113x; 1.0758x over previous
//
#include <hip/hip_runtime.h>

// MechanicsPINN: residual = EI*biharm(f) + GC*lap(f) + KC*f - P,
// f = MLP(x) 2->256->512->1024->65536, B=64, grid 256x256. All inputs fp32.
// Round 12: m201-style GEMM schedule: 256-thr block, SHARED 128-col x 32-k
// W tile (512-B HBM segments) + shared 4-KB A tile, global_load_lds staging,
// double-buffered, raw s_barrier + counted inline vmcnt(5) (never drains in
// the main loop). A staged once per block (halves L2 A-traffic vs R9).
// W source-side bit-4 XOR swizzle -> 2-way LDS reads; A m^(g<<2) swizzle.

#define BATCH 64
#define NPIX 65536

typedef __attribute__((ext_vector_type(8))) short short8_t;  // bf16 x8 (4 VGPR)
typedef __attribute__((ext_vector_type(4))) float f32x4;

__device__ __forceinline__ short f2bf(float x) {  // fp32 -> bf16 RNE
    unsigned u = __float_as_uint(x);
    unsigned r = (u + 0x7fffu + ((u >> 16) & 1u)) >> 16;
    return (short)r;
}

// -------- Fused layers 1+2: h2 = relu(relu(x@W1+b1) @ W2 + b2) --------
__global__ void k_layer12(const float* __restrict__ x, const float* __restrict__ W1,
                          const float* __restrict__ b1, const float* __restrict__ W2,
                          const float* __restrict__ b2, float* __restrict__ h2) {
    __shared__ float As[16][64];
    __shared__ float Ws[64][16];
    int tid = threadIdx.x;
    int tn = tid & 15, tm = tid >> 4;
    int n0 = blockIdx.x * 16, m0 = blockIdx.y * 16;
    float acc = 0.f;
    for (int k0 = 0; k0 < 256; k0 += 64) {
#pragma unroll
        for (int j = 0; j < 4; ++j) {          // build h1 16x64 tile on the fly
            int e = j * 256 + tid;
            int m = m0 + (e >> 6), kk = k0 + (e & 63);
            float v = x[m * 2 + 0] * W1[kk] + x[m * 2 + 1] * W1[256 + kk] + b1[kk];
            As[e >> 6][e & 63] = v > 0.f ? v : 0.f;
        }
#pragma unroll
        for (int j = 0; j < 4; ++j) {          // stage W2 64x16
            int e = j * 256 + tid;
            Ws[e >> 4][e & 15] = W2[(k0 + (e >> 4)) * 512 + n0 + (e & 15)];
        }
        __syncthreads();
#pragma unroll
        for (int k = 0; k < 64; ++k)
            acc += As[tm][k] * Ws[k][tn];
        __syncthreads();
    }
    acc += b2[n0 + tn];
    acc = acc > 0.f ? acc : 0.f;
    h2[(m0 + tm) * 512 + n0 + tn] = acc;
}

// -------- Layer 3: h3b(bf16) = relu(h2 @ W3 + b3), K=512, N=1024 --------
__global__ void k_layer3(const float* __restrict__ A, const float* __restrict__ Wt,
                         const float* __restrict__ bias, short* __restrict__ out_bf) {
    __shared__ float As[16][64];
    __shared__ float Ws[64][16];
    int tid = threadIdx.x;
    int tn = tid & 15, tm = tid >> 4;
    int n0 = blockIdx.x * 16, m0 = blockIdx.y * 16;
    float acc = 0.f;
    for (int k0 = 0; k0 < 512; k0 += 64) {
#pragma unroll
        for (int j = 0; j < 4; ++j) {
            int e = j * 256 + tid;
            As[e >> 6][e & 63] = A[(m0 + (e >> 6)) * 512 + k0 + (e & 63)];
        }
#pragma unroll
        for (int j = 0; j < 4; ++j) {
            int e = j * 256 + tid;
            Ws[e >> 4][e & 15] = Wt[(k0 + (e >> 4)) * 1024 + n0 + (e & 15)];
        }
        __syncthreads();
#pragma unroll
        for (int k = 0; k < 64; ++k)
            acc += As[tm][k] * Ws[k][tn];
        __syncthreads();
    }
    acc += bias[n0 + tn];
    acc = acc > 0.f ? acc : 0.f;
    out_bf[(m0 + tm) * 1024 + n0 + tn] = f2bf(acc);
}

// ---------- Main GEMM: f = h3b @ W4 + b4 (bf16 MFMA, M=64,N=65536,K=1024) ----
// 256 thr / 4 waves; block tile = 128 cols x 64 m. Wave w owns cols
// w*32..w*32+31 (2 col-tiles x 4 m-tiles = 8 MFMA per 32-k step).
// Double-buffered shared staging via global_load_lds; 5 loads/thread/step;
// inline s_waitcnt vmcnt(5) + raw s_barrier (no drain in main loop).
__global__ __launch_bounds__(256) void k_gemm_mfma(
        const short* __restrict__ A,     // h3 bf16 [64][1024]
        const float* __restrict__ W,     // W4 fp32 [1024][65536]
        const float* __restrict__ bias,  // [65536]
        float* __restrict__ f) {         // [64][65536]
    __shared__ float Wt[2][32 * 128];    // 16 KB per buffer, [k][col^swz]
    __shared__ short At[2][4 * 64 * 8];  // 4 KB per buffer, [kq][m^swz][8]
    const int tid = threadIdx.x;
    const int w = tid >> 6;
    const int lane = tid & 63;
    const int lr = lane & 15;
    const int g = lane >> 4;             // k-group 0..3
    const int n0 = blockIdx.x * 128;

    f32x4 acc[4][2];                     // [m-tile][col-tile]
#pragma unroll
    for (int a = 0; a < 4; ++a)
#pragma unroll
        for (int b = 0; b < 2; ++b)
            acc[a][b] = {0.f, 0.f, 0.f, 0.f};

    // stage step s into buffer b: 4 W-chunks + 1 A-chunk per thread (16B each)
    auto stage = [&](int b, int s) {
#pragma unroll
        for (int i = 0; i < 4; ++i) {
            int c = i * 256 + tid;                 // 0..1023
            int k = c >> 5;                        // 0..31
            int q4 = (c & 31) * 4;                 // float col-group
            int csw = q4 ^ (((k >> 3) & 1) << 4);  // source pre-swizzle (bit4)
            const float* src = W + (size_t)(s * 32 + k) * NPIX + n0 + csw;
            __builtin_amdgcn_global_load_lds(
                (const __attribute__((address_space(1))) void*)src,
                (__attribute__((address_space(3))) void*)((char*)&Wt[b][0] + c * 16),
                16, 0, 0);
        }
        {
            int kq = tid >> 6;                     // 0..3
            int ms = tid & 63;
            int md = ms ^ (kq << 2);               // source m pre-swizzle
            const short* asrc = A + md * 1024 + s * 32 + kq * 8;
            __builtin_amdgcn_global_load_lds(
                (const __attribute__((address_space(1))) void*)asrc,
                (__attribute__((address_space(3))) void*)((char*)&At[b][0] + tid * 16),
                16, 0, 0);
        }
    };

    stage(0, 0);

    for (int s = 0; s < 32; ++s) {
        const int cur = s & 1;
        if (s < 31) {
            stage(cur ^ 1, s + 1);
            asm volatile("s_waitcnt vmcnt(5)" ::: "memory");  // stage(s) landed
        } else {
            asm volatile("s_waitcnt vmcnt(0)" ::: "memory");
        }
        __builtin_amdgcn_sched_barrier(0);
        __builtin_amdgcn_s_barrier();    // everyone's stage(s) landed

        // A-frags: [kq=g][(mrow^(g<<2))]
        short8_t afr[4];
#pragma unroll
        for (int mt = 0; mt < 4; ++mt) {
            int mrow = mt * 16 + lr;
            afr[mt] = *(const short8_t*)((const short*)&At[cur][0] +
                                         g * 512 + (mrow ^ (g << 2)) * 8);
        }
#pragma unroll
        for (int t = 0; t < 2; ++t) {
            const int col = w * 32 + t * 16 + lr;
            const int csw = col ^ ((g & 1) << 4);  // undo bit-4 swizzle
            short8_t bfr;
#pragma unroll
            for (int j = 0; j < 8; ++j)
                bfr[j] = f2bf(Wt[cur][(g * 8 + j) * 128 + csw]);
#pragma unroll
            for (int mt = 0; mt < 4; ++mt)
                acc[mt][t] = __builtin_amdgcn_mfma_f32_16x16x32_bf16(afr[mt], bfr, acc[mt][t], 0, 0, 0);
        }
        __builtin_amdgcn_s_barrier();    // all reads of cur done before overwrite
    }

    // C/D layout: col = lane&15, row = (lane>>4)*4 + reg
#pragma unroll
    for (int t = 0; t < 2; ++t) {
        const int col = n0 + w * 32 + t * 16 + lr;
        float bb = bias[col];
#pragma unroll
        for (int mt = 0; mt < 4; ++mt) {
            int rowb = mt * 16 + g * 4;
#pragma unroll
            for (int r = 0; r < 4; ++r)
                f[(size_t)(rowb + r) * NPIX + col] = acc[mt][t][r] + bb;
        }
    }
}

// --------------------------- Stencil ---------------------------
// residual = biharm + lap + f - P; reflect-1 index reflection.
#define ROWS 16
__device__ __forceinline__ int rfl(int i) {
    return i < 0 ? -i : (i > 255 ? 510 - i : i);
}
__global__ void k_stencil(const float* __restrict__ f, const float* __restrict__ P,
                          float* __restrict__ out) {
    __shared__ float fs[ROWS + 4][256];
    int x = threadIdx.x;
    int y0 = blockIdx.x * ROWS;
    int b = blockIdx.y;
    const float* fb = f + (size_t)b * NPIX;
    for (int t = 0; t < ROWS + 4; ++t) {
        int gy = rfl(y0 - 2 + t);
        fs[t][x] = fb[gy * 256 + x];
    }
    __syncthreads();

    int xm = x == 0 ? 1 : x - 1;
    int xp = x == 255 ? 254 : x + 1;

    auto lapAt = [&](int j, int i) {
        int s = j - y0 + 2;
        int sm = rfl(j - 1) - y0 + 2;
        int sp = rfl(j + 1) - y0 + 2;
        int im = i == 0 ? 1 : i - 1;
        int ip = i == 255 ? 254 : i + 1;
        float c = fs[s][i];
        return (fs[sm][i] - 2.f * c + fs[sp][i]) + (fs[s][im] - 2.f * c + fs[s][ip]);
    };

    for (int r = 0; r < ROWS; ++r) {
        int y = y0 + r;
        float lc = lapAt(y, x);
        float lym = lapAt(rfl(y - 1), x);
        float lyp = lapAt(rfl(y + 1), x);
        float lxm = lapAt(y, xm);
        float lxp = lapAt(y, xp);
        float bih = (lym - 2.f * lc + lyp) + (lxm - 2.f * lc + lxp);
        float fc = fs[r + 2][x];
        size_t idx = (size_t)b * NPIX + y * 256 + x;
        out[idx] = bih + lc + fc - P[idx];
    }
}

extern "C" void kernel_launch(void* const* d_in, const int* in_sizes, int n_in,
                              void* d_out, int out_size, void* d_ws, size_t ws_size,
                              hipStream_t stream) {
    const float* x  = (const float*)d_in[0];
    const float* P  = (const float*)d_in[1];
    const float* W1 = (const float*)d_in[2];
    const float* b1 = (const float*)d_in[3];
    const float* W2 = (const float*)d_in[4];
    const float* b2 = (const float*)d_in[5];
    const float* W3 = (const float*)d_in[6];
    const float* b3 = (const float*)d_in[7];
    const float* W4 = (const float*)d_in[8];
    const float* b4 = (const float*)d_in[9];
    float* out = (float*)d_out;

    char* ws = (char*)d_ws;
    float* h2  = (float*)(ws);                      // 64*512*4  = 128 KB
    short* h3b = (short*)(ws + (128 << 10));        // 64*1024*2 = 128 KB (bf16)
    float* f   = (float*)(ws + (256 << 10));        // 64*65536*4 = 16 MB

    k_layer12<<<dim3(512 / 16, 4), 256, 0, stream>>>(x, W1, b1, W2, b2, h2);
    k_layer3<<<dim3(1024 / 16, 4), 256, 0, stream>>>(h2, W3, b3, h3b);
    k_gemm_mfma<<<NPIX / 128, 256, 0, stream>>>(h3b, W4, b4, f);
    k_stencil<<<dim3(256 / ROWS, BATCH), 256, 0, stream>>>(f, P, out);
}